// Round 8
// baseline (261.848 us; speedup 1.0000x reference)
//
#include <hip/hip_runtime.h>
#include <math.h>

// B=2, H=8, L=2048, E=512, d=64
constexpr int CL = 2048;
constexpr int NROW = 32768;
constexpr float SCALE = 1.0f / 2048.0f;
constexpr float TWO_PI = 6.283185307179586f;

typedef short short8 __attribute__((ext_vector_type(8)));
typedef float floatx4 __attribute__((ext_vector_type(4)));

__device__ inline unsigned short f2bf(float f) {
  union { float f; unsigned u; } c; c.f = f;
  unsigned u = c.u + 0x7FFF + ((c.u >> 16) & 1);
  return (unsigned short)(u >> 16);
}
__device__ inline float bf2f(unsigned short h) {
  union { unsigned u; float f; } c; c.u = ((unsigned)h) << 16;
  return c.f;
}

// ---------------- workspace ----------------
constexpr size_t F_C0S = 0;
constexpr size_t F_C0Z = F_C0S + NROW;
constexpr size_t F_END = F_C0Z + NROW;
constexpr size_t U_CH  = 0;
constexpr size_t U_CL  = U_CH + (size_t)NROW * 64;
constexpr size_t U_BF  = U_CL + (size_t)NROW * 64;
constexpr size_t U_VF  = U_BF + (size_t)2 * 131072;
constexpr size_t BF_SPLIT = 131072;
constexpr size_t VF_PLANE = 2097152;

// ================================================================ mega launch 1
// blocks [0,64):   Bf basis-fragment table
// blocks [64,576): kv V-fragment build (A-operand layout, hi/lo planes)
// blocks [576,1088): fused DFT+coef, twiddles computed into own LDS
__launch_bounds__(256)
__global__ void mega1(const float* __restrict__ q, const float* __restrict__ kin,
                      const float* __restrict__ values,
                      unsigned short* __restrict__ Bf, unsigned short* __restrict__ Vf,
                      unsigned short* __restrict__ Ch, unsigned short* __restrict__ Cl,
                      float* __restrict__ c0s) {
  __shared__ char smem[16640];
  int tid = threadIdx.x;
  int blk = blockIdx.x;
  if (blk < 64) {
    int gid = blk * 256 + tid;
    int lt = gid >> 7, rem = gid & 127, ks = rem >> 6, lane = rem & 63;
    int qd = lane >> 4, n = lane & 15;
    int t = lt * 16 + n;
    size_t base = ((size_t)((lt * 2 + ks) * 64 + lane)) * 8;
    for (int j = 0; j < 8; ++j) {
      int kr = ks * 32 + qd * 8 + j;
      int freq = (kr < 32) ? (kr + 1) : (kr - 31);
      int ph = (freq * t) & (CL - 1);
      float ang = (float)ph * (TWO_PI / (float)CL);
      float val = (kr < 32) ? cosf(ang) : sinf(ang);
      unsigned short hi = f2bf(val);
      Bf[base + j] = hi;
      Bf[BF_SPLIT + base + j] = f2bf(val - bf2f(hi));
    }
    return;
  }
  if (blk < 576) {
    // V tile [64 s][64 d] -> A-operand frags: frag f = sh*4+dt;
    // elem[lane*8+j] = V[s = st*64 + sh*32 + qd*8 + j][d = dt*16 + n]
    float* Vt = (float*)smem;                    // [64][65]
    int idx = blk - 64;
    int bh = idx >> 5, st = idx & 31;
    int b = bh >> 3, h = bh & 7;
    {
      int sl = tid >> 2, dq = (tid & 3) * 16;
      const float4* src = (const float4*)(values + ((size_t)(b * 2048 + st * 64 + sl)) * 512 + h * 64 + dq);
#pragma unroll
      for (int m = 0; m < 4; ++m) {
        float4 t4 = src[m];
        int base = sl * 65 + dq + m * 4;
        Vt[base] = t4.x; Vt[base + 1] = t4.y; Vt[base + 2] = t4.z; Vt[base + 3] = t4.w;
      }
    }
    __syncthreads();
#pragma unroll
    for (int iter = 0; iter < 2; ++iter) {
      int it = iter * 256 + tid;
      int lane = it & 63, f = (it >> 6) & 7;
      int sh = f >> 2, dt = f & 3;
      int qd = lane >> 4, n = lane & 15;
      short8 hi, lo;
#pragma unroll
      for (int j = 0; j < 8; ++j) {
        float v2 = Vt[(sh * 32 + qd * 8 + j) * 65 + dt * 16 + n];
        unsigned short h2 = f2bf(v2);
        hi[j] = (short)h2; lo[j] = (short)f2bf(v2 - bf2f(h2));
      }
      size_t off = (((size_t)(bh * 32 + st)) * 8 + f) * 512 + lane * 8;
      *(short8*)(Vf + off) = hi;
      *(short8*)(Vf + VF_PLANE + off) = lo;
    }
    return;
  }
  // ---- fused DFT + coef. Block = 8 s x 8 h of one b (64 rows).
  unsigned short* Tws = (unsigned short*)smem;   // 4 planes x 2048
  {
    int g0 = tid * 8;
    int lane_g = (g0 >> 3) & 63, ksp_g = (g0 >> 9) & 1, ct_g = g0 >> 10;
    int f = ct_g * 16 + (lane_g & 15);
    int cb = ksp_g * 32 + ((lane_g >> 4) & 3) * 8;
#pragma unroll
    for (int j = 0; j < 8; ++j) {
      float ang = (float)((f * (cb + j)) & 63) * (TWO_PI / 64.0f);
      float s1, c1;
      sincosf(ang, &s1, &c1);
      float re = c1, im = -s1;
      unsigned short rh = f2bf(re), ih = f2bf(im);
      Tws[g0 + j] = rh;        Tws[2048 + g0 + j] = f2bf(re - bf2f(rh));
      Tws[4096 + g0 + j] = ih; Tws[6144 + g0 + j] = f2bf(im - bf2f(ih));
    }
  }
  __syncthreads();
  int w = tid >> 6, lane = tid & 63, qd = lane >> 4, n = lane & 15;
  int blk1 = blk - 576;
  int b = blk1 >> 8, s0 = (blk1 & 255) * 8;
  int sA = s0 + w * 2 + (n >> 3), hA = n & 7;
  const float* qp = q + ((size_t)(b * 2048 + sA)) * 512 + hA * 64 + qd * 8;
  const float* kp = kin + ((size_t)(b * 2048 + sA)) * 512 + hA * 64 + qd * 8;
  float qv[16], kv[16];
#pragma unroll
  for (int ksp = 0; ksp < 2; ++ksp) {
    float4 a0 = *(const float4*)(qp + ksp * 32);
    float4 a1 = *(const float4*)(qp + ksp * 32 + 4);
    float4 b0 = *(const float4*)(kp + ksp * 32);
    float4 b1 = *(const float4*)(kp + ksp * 32 + 4);
    qv[ksp*8+0]=a0.x; qv[ksp*8+1]=a0.y; qv[ksp*8+2]=a0.z; qv[ksp*8+3]=a0.w;
    qv[ksp*8+4]=a1.x; qv[ksp*8+5]=a1.y; qv[ksp*8+6]=a1.z; qv[ksp*8+7]=a1.w;
    kv[ksp*8+0]=b0.x; kv[ksp*8+1]=b0.y; kv[ksp*8+2]=b0.z; kv[ksp*8+3]=b0.w;
    kv[ksp*8+4]=b1.x; kv[ksp*8+5]=b1.y; kv[ksp*8+6]=b1.z; kv[ksp*8+7]=b1.w;
  }
  float aq = 0.0f, ak = 0.0f;
#pragma unroll
  for (int i = 0; i < 16; ++i) {
    float sg = (i & 1) ? -1.0f : 1.0f;
    aq += sg * qv[i]; ak += sg * kv[i];
  }
  aq += __shfl_xor(aq, 16); aq += __shfl_xor(aq, 32);
  ak += __shfl_xor(ak, 16); ak += __shfl_xor(ak, 32);
  short8 Aqh[2], Aql[2], Akh[2], Akl[2];
#pragma unroll
  for (int ksp = 0; ksp < 2; ++ksp) {
#pragma unroll
    for (int j = 0; j < 8; ++j) {
      unsigned short hq = f2bf(qv[ksp*8+j]);
      Aqh[ksp][j] = (short)hq; Aql[ksp][j] = (short)f2bf(qv[ksp*8+j] - bf2f(hq));
      unsigned short hk = f2bf(kv[ksp*8+j]);
      Akh[ksp][j] = (short)hk; Akl[ksp][j] = (short)f2bf(kv[ksp*8+j] - bf2f(hk));
    }
  }
  float lmr[4] = {0,0,0,0};
  float c0v[4] = {0,0,0,0};
  int hC = (qd * 4) & 7;
  int sC = s0 + w * 2 + (qd >> 1);
#pragma unroll
  for (int ct = 0; ct < 2; ++ct) {
    short8 Brh[2], Brl[2], Bih[2], Bil[2];
#pragma unroll
    for (int ksp = 0; ksp < 2; ++ksp) {
      size_t off = (size_t)ct * 1024 + ksp * 512 + lane * 8;
      Brh[ksp] = *(const short8*)(Tws + off);
      Brl[ksp] = *(const short8*)(Tws + 2048 + off);
      Bih[ksp] = *(const short8*)(Tws + 4096 + off);
      Bil[ksp] = *(const short8*)(Tws + 6144 + off);
    }
    floatx4 qre = {0,0,0,0}, qim = {0,0,0,0}, kre = {0,0,0,0}, kim = {0,0,0,0};
#pragma unroll
    for (int ksp = 0; ksp < 2; ++ksp) {
      qre = __builtin_amdgcn_mfma_f32_16x16x32_bf16(Aqh[ksp], Brh[ksp], qre, 0,0,0);
      qre = __builtin_amdgcn_mfma_f32_16x16x32_bf16(Aqh[ksp], Brl[ksp], qre, 0,0,0);
      qre = __builtin_amdgcn_mfma_f32_16x16x32_bf16(Aql[ksp], Brh[ksp], qre, 0,0,0);
      qim = __builtin_amdgcn_mfma_f32_16x16x32_bf16(Aqh[ksp], Bih[ksp], qim, 0,0,0);
      qim = __builtin_amdgcn_mfma_f32_16x16x32_bf16(Aqh[ksp], Bil[ksp], qim, 0,0,0);
      qim = __builtin_amdgcn_mfma_f32_16x16x32_bf16(Aql[ksp], Bih[ksp], qim, 0,0,0);
      kre = __builtin_amdgcn_mfma_f32_16x16x32_bf16(Akh[ksp], Brh[ksp], kre, 0,0,0);
      kre = __builtin_amdgcn_mfma_f32_16x16x32_bf16(Akh[ksp], Brl[ksp], kre, 0,0,0);
      kre = __builtin_amdgcn_mfma_f32_16x16x32_bf16(Akl[ksp], Brh[ksp], kre, 0,0,0);
      kim = __builtin_amdgcn_mfma_f32_16x16x32_bf16(Akh[ksp], Bih[ksp], kim, 0,0,0);
      kim = __builtin_amdgcn_mfma_f32_16x16x32_bf16(Akh[ksp], Bil[ksp], kim, 0,0,0);
      kim = __builtin_amdgcn_mfma_f32_16x16x32_bf16(Akl[ksp], Bih[ksp], kim, 0,0,0);
    }
    float xre[4], xim[4], tre = 0, tim = 0;
#pragma unroll
    for (int r = 0; r < 4; ++r) {
      xre[r] = qre[r] * kre[r] + qim[r] * kim[r];
      xim[r] = qim[r] * kre[r] - qre[r] * kim[r];
      tre += xre[r]; tim += xim[r];
    }
    tre += __shfl_xor(tre, 16);
    tim += __shfl_xor(tim, 16);
    float mre = tre * 0.125f, mim = tim * 0.125f;
#pragma unroll
    for (int r = 0; r < 4; ++r) {
      float yre = xre[r] - mre, yim = xim[r] - mim;
      if (ct == 0 && n == 0) {
        c0v[r] = yre * SCALE;
      } else {
        int f = ct * 16 + n;
        float a = 2.0f * yre * SCALE, bb = -2.0f * yim * SCALE;
        size_t rowid = (size_t)((b * 8 + hC + r) * 2048 + sC);
        unsigned short ah = f2bf(a);
        Ch[rowid * 64 + f - 1] = ah;
        Cl[rowid * 64 + f - 1] = f2bf(a - bf2f(ah));
        unsigned short bh2 = f2bf(bb);
        Ch[rowid * 64 + 32 + f - 1] = bh2;
        Cl[rowid * 64 + 32 + f - 1] = f2bf(bb - bf2f(bh2));
        lmr[r] += fabsf(a) + fabsf(bb);
      }
    }
  }
  float X32 = aq * ak;
  float m32 = X32;
  m32 += __shfl_xor(m32, 1); m32 += __shfl_xor(m32, 2); m32 += __shfl_xor(m32, 4);
  float A32 = 2.0f * (X32 - m32 * 0.125f) * SCALE;
  if (qd == 0) {
    size_t rowid = (size_t)((b * 8 + (n & 7)) * 2048 + s0 + w * 2 + (n >> 3));
    unsigned short ah = f2bf(A32);
    Ch[rowid * 64 + 31] = ah;
    Cl[rowid * 64 + 31] = f2bf(A32 - bf2f(ah));
    Ch[rowid * 64 + 63] = 0;
    Cl[rowid * 64 + 63] = 0;
  }
  float absA32 = fabsf(A32);
#pragma unroll
  for (int r = 0; r < 4; ++r) {
    lmr[r] += __shfl_xor(lmr[r], 1);
    lmr[r] += __shfl_xor(lmr[r], 2);
    lmr[r] += __shfl_xor(lmr[r], 4);
    lmr[r] += __shfl_xor(lmr[r], 8);
  }
  int qb = lane & 48;
#pragma unroll
  for (int r = 0; r < 4; ++r) {
    float a32r = __shfl(absA32, qb + (qb >> 2) + r);
    if (n == 0) {
      float M = fabsf(c0v[r]) + lmr[r] + a32r;
      size_t rowid = (size_t)((b * 8 + hC + r) * 2048 + sC);
      c0s[rowid] = c0v[r] - M;
    }
  }
}

// ---------------------------------------------------------------- k3: c0z = c0 - log(Z)
__launch_bounds__(256)
__global__ void k3_z(const unsigned short* __restrict__ Ch, const unsigned short* __restrict__ Cl,
                     const float* __restrict__ c0s, const unsigned short* __restrict__ Bf,
                     float* __restrict__ c0z) {
  __shared__ float Zl[64];
  int tid = threadIdx.x;
  int w = tid >> 6, lane = tid & 63, q = lane >> 4, n = lane & 15;
  int rowbase = blockIdx.x * 64;
  short8 Ah[4][2], Al[4][2];
#pragma unroll
  for (int c = 0; c < 4; ++c)
#pragma unroll
    for (int ksp = 0; ksp < 2; ++ksp) {
      size_t srow = (size_t)(rowbase + c * 16 + n);
      Ah[c][ksp] = *(const short8*)(Ch + srow * 64 + ksp * 32 + q * 8);
      Al[c][ksp] = *(const short8*)(Cl + srow * 64 + ksp * 32 + q * 8);
    }
  float c0r[4][4], zacc[4][4];
#pragma unroll
  for (int c = 0; c < 4; ++c)
#pragma unroll
    for (int r = 0; r < 4; ++r) {
      c0r[c][r] = c0s[rowbase + c * 16 + q * 4 + r];
      zacc[c][r] = 0.0f;
    }
  if (tid < 64) Zl[tid] = 0.0f;
  const unsigned short* BfL = Bf + BF_SPLIT;
  for (int lt = w; lt < 128; lt += 4) {
    size_t b0 = ((size_t)(lt * 2 + 0) * 64 + lane) * 8;
    size_t b1 = ((size_t)(lt * 2 + 1) * 64 + lane) * 8;
    short8 Bh0 = *(const short8*)(Bf + b0);
    short8 Bh1 = *(const short8*)(Bf + b1);
    short8 Bl0 = *(const short8*)(BfL + b0);
    short8 Bl1 = *(const short8*)(BfL + b1);
#pragma unroll
    for (int c = 0; c < 4; ++c) {
      floatx4 y = {0.f, 0.f, 0.f, 0.f};
      y = __builtin_amdgcn_mfma_f32_16x16x32_bf16(Ah[c][0], Bh0, y, 0, 0, 0);
      y = __builtin_amdgcn_mfma_f32_16x16x32_bf16(Ah[c][1], Bh1, y, 0, 0, 0);
      y = __builtin_amdgcn_mfma_f32_16x16x32_bf16(Ah[c][0], Bl0, y, 0, 0, 0);
      y = __builtin_amdgcn_mfma_f32_16x16x32_bf16(Ah[c][1], Bl1, y, 0, 0, 0);
      y = __builtin_amdgcn_mfma_f32_16x16x32_bf16(Al[c][0], Bh0, y, 0, 0, 0);
      y = __builtin_amdgcn_mfma_f32_16x16x32_bf16(Al[c][1], Bh1, y, 0, 0, 0);
#pragma unroll
      for (int r = 0; r < 4; ++r) zacc[c][r] += __expf(y[r] + c0r[c][r]);
    }
  }
  __syncthreads();
#pragma unroll
  for (int c = 0; c < 4; ++c)
#pragma unroll
    for (int r = 0; r < 4; ++r) {
#pragma unroll
      for (int m = 1; m < 16; m <<= 1) zacc[c][r] += __shfl_xor(zacc[c][r], m, 16);
      if (n == 0) atomicAdd(&Zl[c * 16 + q * 4 + r], zacc[c][r]);
    }
  __syncthreads();
  if (tid < 64) c0z[rowbase + tid] = c0s[rowbase + tid] - __logf(Zl[tid]);
}

// ---------------------------------------------------------------- k4: barrier-free K-loop
// Block = (b,h) x 32 l-cols; wave w: s-half sh=w>>1, l-16 slice lq=w&1.
// Per tile: E-MFMA for (32 s x 16 l) -> exp -> IN-REGISTER transpose (8 shfl +
// 4 select) to B-operand layout -> PV mfma(A=V^T frag, B=E). Partial-s accs;
// single LDS reduction + ONE barrier at kernel end. No vmcnt(0) drains in loop.
__launch_bounds__(256, 3)
__global__ void k4_out(const unsigned short* __restrict__ Ch, const unsigned short* __restrict__ Cl,
                       const float* __restrict__ c0z, const unsigned short* __restrict__ Bf,
                       const unsigned short* __restrict__ Vf, float* __restrict__ out) {
  __shared__ float Red[2][16][64];
  int tid = threadIdx.x;
  int w = tid >> 6, lane = tid & 63, qd = lane >> 4, n = lane & 15;
  int lq = w & 1, sh = w >> 1;
  int bh = blockIdx.x, b = bh >> 3, h = bh & 7;
  int ltw = blockIdx.y * 2 + lq;                 // this wave's l-16 tile
  const unsigned short* BfL = Bf + BF_SPLIT;
  const unsigned short* VfL = Vf + VF_PLANE;
  short8 Bbh[2], Bbl[2];
#pragma unroll
  for (int ksp = 0; ksp < 2; ++ksp) {
    size_t bo = ((size_t)(ltw * 2 + ksp) * 64 + lane) * 8;
    Bbh[ksp] = *(const short8*)(Bf + bo);
    Bbl[ksp] = *(const short8*)(BfL + bo);
  }
  floatx4 acc[4];
#pragma unroll
  for (int dt = 0; dt < 4; ++dt) acc[dt] = (floatx4){0.f, 0.f, 0.f, 0.f};
  int L0 = 32 * (qd & 1) + n;                    // transpose source lanes
  int L1 = L0 + 16;
  bool hiFrag = (qd >> 1) != 0;

  for (int st = 0; st < 32; ++st) {
    int rowb = bh * 2048 + st * 64;
    // V loads (A-operand frags; used last)
    short8 Vh[4], Vl[4];
#pragma unroll
    for (int dt = 0; dt < 4; ++dt) {
      size_t vo = (((size_t)(bh * 32 + st)) * 8 + sh * 4 + dt) * 512 + lane * 8;
      Vh[dt] = *(const short8*)(Vf + vo);
      Vl[dt] = *(const short8*)(VfL + vo);
    }
    // A loads + E-MFMA + exp + pack (two 16-s subtiles)
    unsigned P[2][2];
#pragma unroll
    for (int a = 0; a < 2; ++a) {
      size_t srow = (size_t)(rowb + sh * 32 + a * 16 + n);
      short8 Ah0 = *(const short8*)(Ch + srow * 64 + qd * 8);
      short8 Ah1 = *(const short8*)(Ch + srow * 64 + 32 + qd * 8);
      short8 Al0 = *(const short8*)(Cl + srow * 64 + qd * 8);
      short8 Al1 = *(const short8*)(Cl + srow * 64 + 32 + qd * 8);
      float4 c04 = *(const float4*)(c0z + rowb + sh * 32 + a * 16 + qd * 4);
      floatx4 y = {0.f, 0.f, 0.f, 0.f};
      y = __builtin_amdgcn_mfma_f32_16x16x32_bf16(Ah0, Bbh[0], y, 0, 0, 0);
      y = __builtin_amdgcn_mfma_f32_16x16x32_bf16(Ah1, Bbh[1], y, 0, 0, 0);
      y = __builtin_amdgcn_mfma_f32_16x16x32_bf16(Ah0, Bbl[0], y, 0, 0, 0);
      y = __builtin_amdgcn_mfma_f32_16x16x32_bf16(Ah1, Bbl[1], y, 0, 0, 0);
      y = __builtin_amdgcn_mfma_f32_16x16x32_bf16(Al0, Bbh[0], y, 0, 0, 0);
      y = __builtin_amdgcn_mfma_f32_16x16x32_bf16(Al1, Bbh[1], y, 0, 0, 0);
      unsigned short e0 = f2bf(__expf(y[0] + c04.x));
      unsigned short e1 = f2bf(__expf(y[1] + c04.y));
      unsigned short e2 = f2bf(__expf(y[2] + c04.z));
      unsigned short e3 = f2bf(__expf(y[3] + c04.w));
      P[a][0] = (unsigned)e0 | ((unsigned)e1 << 16);
      P[a][1] = (unsigned)e2 | ((unsigned)e3 << 16);
    }
    // In-register C-layout -> B-operand transpose (verified mapping):
    // target lane (qd,n) needs s = 8*qd + {0..7} at l = n.
    unsigned q00 = (unsigned)__shfl((int)P[0][0], L0);
    unsigned q01 = (unsigned)__shfl((int)P[0][1], L0);
    unsigned q02 = (unsigned)__shfl((int)P[0][0], L1);
    unsigned q03 = (unsigned)__shfl((int)P[0][1], L1);
    unsigned q10 = (unsigned)__shfl((int)P[1][0], L0);
    unsigned q11 = (unsigned)__shfl((int)P[1][1], L0);
    unsigned q12 = (unsigned)__shfl((int)P[1][0], L1);
    unsigned q13 = (unsigned)__shfl((int)P[1][1], L1);
    union { uint4 u; short8 s; } Eb;
    Eb.u.x = hiFrag ? q10 : q00;
    Eb.u.y = hiFrag ? q11 : q01;
    Eb.u.z = hiFrag ? q12 : q02;
    Eb.u.w = hiFrag ? q13 : q03;
    // PV: D[d, l] partial over this wave's 32 s
#pragma unroll
    for (int dt = 0; dt < 4; ++dt) {
      acc[dt] = __builtin_amdgcn_mfma_f32_16x16x32_bf16(Vh[dt], Eb.s, acc[dt], 0, 0, 0);
      acc[dt] = __builtin_amdgcn_mfma_f32_16x16x32_bf16(Vl[dt], Eb.s, acc[dt], 0, 0, 0);
    }
  }
  // Cross-wave s-half reduction (the only barrier in the kernel)
  if (sh == 1) {
#pragma unroll
    for (int dt = 0; dt < 4; ++dt)
#pragma unroll
      for (int r = 0; r < 4; ++r)
        Red[lq][dt * 4 + r][lane] = acc[dt][r];
  }
  __syncthreads();
  if (sh == 0) {
#pragma unroll
    for (int dt = 0; dt < 4; ++dt) {
#pragma unroll
      for (int r = 0; r < 4; ++r) {
        float v2 = acc[dt][r] + Red[lq][dt * 4 + r][lane];
        // d = dt*16 + qd*4 + r ; l = blockIdx.y*32 + lq*16 + n
        out[((size_t)((b * 64 + dt * 16 + qd * 4 + r) * 8 + h)) * 2048
            + blockIdx.y * 32 + lq * 16 + n] = v2;
      }
    }
  }
}

extern "C" void kernel_launch(void* const* d_in, const int* in_sizes, int n_in,
                              void* d_out, int out_size, void* d_ws, size_t ws_size,
                              hipStream_t stream) {
  const float* q = (const float*)d_in[0];
  const float* k = (const float*)d_in[1];
  const float* v = (const float*)d_in[2];
  float* out = (float*)d_out;
  float* ws = (float*)d_ws;
  float* c0s = ws + F_C0S;
  float* c0z = ws + F_C0Z;
  unsigned short* ubase = (unsigned short*)(ws + F_END);
  unsigned short* Ch = ubase + U_CH;
  unsigned short* Cl = ubase + U_CL;
  unsigned short* Bf = ubase + U_BF;
  unsigned short* Vf = ubase + U_VF;

  mega1<<<dim3(1088), dim3(256), 0, stream>>>(q, k, v, Bf, Vf, Ch, Cl, c0s);
  k3_z<<<dim3(512), dim3(256), 0, stream>>>(Ch, Cl, c0s, Bf, c0z);
  k4_out<<<dim3(16, 64), dim3(256), 0, stream>>>(Ch, Cl, c0z, Bf, Vf, out);
}

// Round 9
// 156.606 us; speedup vs baseline: 1.6720x; 1.6720x over previous
//
#include <hip/hip_runtime.h>
#include <math.h>

// B=2, H=8, L=2048, E=512, d=64
constexpr int CL = 2048;
constexpr int NROW = 32768;
constexpr float SCALE = 1.0f / 2048.0f;
constexpr float TWO_PI = 6.283185307179586f;

typedef short short8 __attribute__((ext_vector_type(8)));
typedef float floatx4 __attribute__((ext_vector_type(4)));

__device__ inline unsigned short f2bf(float f) {
  union { float f; unsigned u; } c; c.f = f;
  unsigned u = c.u + 0x7FFF + ((c.u >> 16) & 1);
  return (unsigned short)(u >> 16);
}
__device__ inline float bf2f(unsigned short h) {
  union { unsigned u; float f; } c; c.u = ((unsigned)h) << 16;
  return c.f;
}
// XOR swizzle for [rows][64 ushort] LDS tiles: 16B-group g at row r -> g^(r&7).
__device__ inline int sw(int r, int o) {
  return r * 64 + ((((o >> 3) ^ r) & 7) << 3) + (o & 7);
}

// ---------------- workspace ----------------
constexpr size_t F_C0S = 0;
constexpr size_t F_C0Z = F_C0S + NROW;
constexpr size_t F_END = F_C0Z + NROW;
constexpr size_t U_CH  = 0;
constexpr size_t U_CL  = U_CH + (size_t)NROW * 64;
constexpr size_t U_BF  = U_CL + (size_t)NROW * 64;
constexpr size_t U_VF  = U_BF + (size_t)2 * 131072;
constexpr size_t BF_SPLIT = 131072;
constexpr size_t VF_PLANE = 2097152;

// ================================================================ mega launch 1
// blocks [0,64):   Bf basis-fragment table
// blocks [64,576): kv V-fragment build (B-operand layout, hi/lo planes)
// blocks [576,1088): fused DFT+coef, twiddles computed into own LDS
__launch_bounds__(256)
__global__ void mega1(const float* __restrict__ q, const float* __restrict__ kin,
                      const float* __restrict__ values,
                      unsigned short* __restrict__ Bf, unsigned short* __restrict__ Vf,
                      unsigned short* __restrict__ Ch, unsigned short* __restrict__ Cl,
                      float* __restrict__ c0s) {
  __shared__ char smem[16640];
  int tid = threadIdx.x;
  int blk = blockIdx.x;
  if (blk < 64) {
    int gid = blk * 256 + tid;
    int lt = gid >> 7, rem = gid & 127, ks = rem >> 6, lane = rem & 63;
    int qd = lane >> 4, n = lane & 15;
    int t = lt * 16 + n;
    size_t base = ((size_t)((lt * 2 + ks) * 64 + lane)) * 8;
    for (int j = 0; j < 8; ++j) {
      int kr = ks * 32 + qd * 8 + j;
      int freq = (kr < 32) ? (kr + 1) : (kr - 31);
      int ph = (freq * t) & (CL - 1);
      float ang = (float)ph * (TWO_PI / (float)CL);
      float val = (kr < 32) ? cosf(ang) : sinf(ang);
      unsigned short hi = f2bf(val);
      Bf[base + j] = hi;
      Bf[BF_SPLIT + base + j] = f2bf(val - bf2f(hi));
    }
    return;
  }
  if (blk < 576) {
    // V tile [64 s][64 d] -> B-operand frags: frag = dt*2+ksp;
    // elem[lane*8+j] = V[s = ksp*32 + qd*8 + j][d = dt*16 + n]
    float* Vt = (float*)smem;                    // [64][65]
    int idx = blk - 64;
    int bh = idx >> 5, st = idx & 31;
    int b = bh >> 3, h = bh & 7;
    {
      int sl = tid >> 2, dq = (tid & 3) * 16;
      const float4* src = (const float4*)(values + ((size_t)(b * 2048 + st * 64 + sl)) * 512 + h * 64 + dq);
#pragma unroll
      for (int m = 0; m < 4; ++m) {
        float4 t4 = src[m];
        int base = sl * 65 + dq + m * 4;
        Vt[base] = t4.x; Vt[base + 1] = t4.y; Vt[base + 2] = t4.z; Vt[base + 3] = t4.w;
      }
    }
    __syncthreads();
#pragma unroll
    for (int iter = 0; iter < 2; ++iter) {
      int it = iter * 256 + tid;
      int lane = it & 63, ksp = (it >> 6) & 1, dt = it >> 7;
      int qd = lane >> 4, n = lane & 15;
      int d = dt * 16 + n;
      short8 hi, lo;
#pragma unroll
      for (int j = 0; j < 8; ++j) {
        float f = Vt[(ksp * 32 + qd * 8 + j) * 65 + d];
        unsigned short h2 = f2bf(f);
        hi[j] = (short)h2; lo[j] = (short)f2bf(f - bf2f(h2));
      }
      size_t off = (((size_t)(bh * 32 + st)) * 8 + dt * 2 + ksp) * 512 + lane * 8;
      *(short8*)(Vf + off) = hi;
      *(short8*)(Vf + VF_PLANE + off) = lo;
    }
    return;
  }
  // ---- fused DFT + coef. Block = 8 s x 8 h of one b (64 rows).
  unsigned short* Tws = (unsigned short*)smem;   // 4 planes x 2048
  {
    int g0 = tid * 8;
    int lane_g = (g0 >> 3) & 63, ksp_g = (g0 >> 9) & 1, ct_g = g0 >> 10;
    int f = ct_g * 16 + (lane_g & 15);
    int cb = ksp_g * 32 + ((lane_g >> 4) & 3) * 8;
#pragma unroll
    for (int j = 0; j < 8; ++j) {
      float ang = (float)((f * (cb + j)) & 63) * (TWO_PI / 64.0f);
      float s1, c1;
      sincosf(ang, &s1, &c1);
      float re = c1, im = -s1;
      unsigned short rh = f2bf(re), ih = f2bf(im);
      Tws[g0 + j] = rh;        Tws[2048 + g0 + j] = f2bf(re - bf2f(rh));
      Tws[4096 + g0 + j] = ih; Tws[6144 + g0 + j] = f2bf(im - bf2f(ih));
    }
  }
  __syncthreads();
  int w = tid >> 6, lane = tid & 63, qd = lane >> 4, n = lane & 15;
  int blk1 = blk - 576;
  int b = blk1 >> 8, s0 = (blk1 & 255) * 8;
  int sA = s0 + w * 2 + (n >> 3), hA = n & 7;
  const float* qp = q + ((size_t)(b * 2048 + sA)) * 512 + hA * 64 + qd * 8;
  const float* kp = kin + ((size_t)(b * 2048 + sA)) * 512 + hA * 64 + qd * 8;
  float qv[16], kv[16];
#pragma unroll
  for (int ksp = 0; ksp < 2; ++ksp) {
    float4 a0 = *(const float4*)(qp + ksp * 32);
    float4 a1 = *(const float4*)(qp + ksp * 32 + 4);
    float4 b0 = *(const float4*)(kp + ksp * 32);
    float4 b1 = *(const float4*)(kp + ksp * 32 + 4);
    qv[ksp*8+0]=a0.x; qv[ksp*8+1]=a0.y; qv[ksp*8+2]=a0.z; qv[ksp*8+3]=a0.w;
    qv[ksp*8+4]=a1.x; qv[ksp*8+5]=a1.y; qv[ksp*8+6]=a1.z; qv[ksp*8+7]=a1.w;
    kv[ksp*8+0]=b0.x; kv[ksp*8+1]=b0.y; kv[ksp*8+2]=b0.z; kv[ksp*8+3]=b0.w;
    kv[ksp*8+4]=b1.x; kv[ksp*8+5]=b1.y; kv[ksp*8+6]=b1.z; kv[ksp*8+7]=b1.w;
  }
  float aq = 0.0f, ak = 0.0f;
#pragma unroll
  for (int i = 0; i < 16; ++i) {
    float sg = (i & 1) ? -1.0f : 1.0f;
    aq += sg * qv[i]; ak += sg * kv[i];
  }
  aq += __shfl_xor(aq, 16); aq += __shfl_xor(aq, 32);
  ak += __shfl_xor(ak, 16); ak += __shfl_xor(ak, 32);
  short8 Aqh[2], Aql[2], Akh[2], Akl[2];
#pragma unroll
  for (int ksp = 0; ksp < 2; ++ksp) {
#pragma unroll
    for (int j = 0; j < 8; ++j) {
      unsigned short hq = f2bf(qv[ksp*8+j]);
      Aqh[ksp][j] = (short)hq; Aql[ksp][j] = (short)f2bf(qv[ksp*8+j] - bf2f(hq));
      unsigned short hk = f2bf(kv[ksp*8+j]);
      Akh[ksp][j] = (short)hk; Akl[ksp][j] = (short)f2bf(kv[ksp*8+j] - bf2f(hk));
    }
  }
  float lmr[4] = {0,0,0,0};
  float c0v[4] = {0,0,0,0};
  int hC = (qd * 4) & 7;
  int sC = s0 + w * 2 + (qd >> 1);
#pragma unroll
  for (int ct = 0; ct < 2; ++ct) {
    short8 Brh[2], Brl[2], Bih[2], Bil[2];
#pragma unroll
    for (int ksp = 0; ksp < 2; ++ksp) {
      size_t off = (size_t)ct * 1024 + ksp * 512 + lane * 8;
      Brh[ksp] = *(const short8*)(Tws + off);
      Brl[ksp] = *(const short8*)(Tws + 2048 + off);
      Bih[ksp] = *(const short8*)(Tws + 4096 + off);
      Bil[ksp] = *(const short8*)(Tws + 6144 + off);
    }
    floatx4 qre = {0,0,0,0}, qim = {0,0,0,0}, kre = {0,0,0,0}, kim = {0,0,0,0};
#pragma unroll
    for (int ksp = 0; ksp < 2; ++ksp) {
      qre = __builtin_amdgcn_mfma_f32_16x16x32_bf16(Aqh[ksp], Brh[ksp], qre, 0,0,0);
      qre = __builtin_amdgcn_mfma_f32_16x16x32_bf16(Aqh[ksp], Brl[ksp], qre, 0,0,0);
      qre = __builtin_amdgcn_mfma_f32_16x16x32_bf16(Aql[ksp], Brh[ksp], qre, 0,0,0);
      qim = __builtin_amdgcn_mfma_f32_16x16x32_bf16(Aqh[ksp], Bih[ksp], qim, 0,0,0);
      qim = __builtin_amdgcn_mfma_f32_16x16x32_bf16(Aqh[ksp], Bil[ksp], qim, 0,0,0);
      qim = __builtin_amdgcn_mfma_f32_16x16x32_bf16(Aql[ksp], Bih[ksp], qim, 0,0,0);
      kre = __builtin_amdgcn_mfma_f32_16x16x32_bf16(Akh[ksp], Brh[ksp], kre, 0,0,0);
      kre = __builtin_amdgcn_mfma_f32_16x16x32_bf16(Akh[ksp], Brl[ksp], kre, 0,0,0);
      kre = __builtin_amdgcn_mfma_f32_16x16x32_bf16(Akl[ksp], Brh[ksp], kre, 0,0,0);
      kim = __builtin_amdgcn_mfma_f32_16x16x32_bf16(Akh[ksp], Bih[ksp], kim, 0,0,0);
      kim = __builtin_amdgcn_mfma_f32_16x16x32_bf16(Akh[ksp], Bil[ksp], kim, 0,0,0);
      kim = __builtin_amdgcn_mfma_f32_16x16x32_bf16(Akl[ksp], Bih[ksp], kim, 0,0,0);
    }
    float xre[4], xim[4], tre = 0, tim = 0;
#pragma unroll
    for (int r = 0; r < 4; ++r) {
      xre[r] = qre[r] * kre[r] + qim[r] * kim[r];
      xim[r] = qim[r] * kre[r] - qre[r] * kim[r];
      tre += xre[r]; tim += xim[r];
    }
    tre += __shfl_xor(tre, 16);
    tim += __shfl_xor(tim, 16);
    float mre = tre * 0.125f, mim = tim * 0.125f;
#pragma unroll
    for (int r = 0; r < 4; ++r) {
      float yre = xre[r] - mre, yim = xim[r] - mim;
      if (ct == 0 && n == 0) {
        c0v[r] = yre * SCALE;
      } else {
        int f = ct * 16 + n;
        float a = 2.0f * yre * SCALE, bb = -2.0f * yim * SCALE;
        size_t rowid = (size_t)((b * 8 + hC + r) * 2048 + sC);
        unsigned short ah = f2bf(a);
        Ch[rowid * 64 + f - 1] = ah;
        Cl[rowid * 64 + f - 1] = f2bf(a - bf2f(ah));
        unsigned short bh2 = f2bf(bb);
        Ch[rowid * 64 + 32 + f - 1] = bh2;
        Cl[rowid * 64 + 32 + f - 1] = f2bf(bb - bf2f(bh2));
        lmr[r] += fabsf(a) + fabsf(bb);
      }
    }
  }
  float X32 = aq * ak;
  float m32 = X32;
  m32 += __shfl_xor(m32, 1); m32 += __shfl_xor(m32, 2); m32 += __shfl_xor(m32, 4);
  float A32 = 2.0f * (X32 - m32 * 0.125f) * SCALE;
  if (qd == 0) {
    size_t rowid = (size_t)((b * 8 + (n & 7)) * 2048 + s0 + w * 2 + (n >> 3));
    unsigned short ah = f2bf(A32);
    Ch[rowid * 64 + 31] = ah;
    Cl[rowid * 64 + 31] = f2bf(A32 - bf2f(ah));
    Ch[rowid * 64 + 63] = 0;
    Cl[rowid * 64 + 63] = 0;
  }
  float absA32 = fabsf(A32);
#pragma unroll
  for (int r = 0; r < 4; ++r) {
    lmr[r] += __shfl_xor(lmr[r], 1);
    lmr[r] += __shfl_xor(lmr[r], 2);
    lmr[r] += __shfl_xor(lmr[r], 4);
    lmr[r] += __shfl_xor(lmr[r], 8);
  }
  int qb = lane & 48;
#pragma unroll
  for (int r = 0; r < 4; ++r) {
    float a32r = __shfl(absA32, qb + (qb >> 2) + r);
    if (n == 0) {
      float M = fabsf(c0v[r]) + lmr[r] + a32r;
      size_t rowid = (size_t)((b * 8 + hC + r) * 2048 + sC);
      c0s[rowid] = c0v[r] - M;
    }
  }
}

// ---------------------------------------------------------------- k3: c0z = c0 - log(Z)
__launch_bounds__(256)
__global__ void k3_z(const unsigned short* __restrict__ Ch, const unsigned short* __restrict__ Cl,
                     const float* __restrict__ c0s, const unsigned short* __restrict__ Bf,
                     float* __restrict__ c0z) {
  __shared__ float Zl[64];
  int tid = threadIdx.x;
  int w = tid >> 6, lane = tid & 63, q = lane >> 4, n = lane & 15;
  int rowbase = blockIdx.x * 64;
  short8 Ah[4][2], Al[4][2];
#pragma unroll
  for (int c = 0; c < 4; ++c)
#pragma unroll
    for (int ksp = 0; ksp < 2; ++ksp) {
      size_t srow = (size_t)(rowbase + c * 16 + n);
      Ah[c][ksp] = *(const short8*)(Ch + srow * 64 + ksp * 32 + q * 8);
      Al[c][ksp] = *(const short8*)(Cl + srow * 64 + ksp * 32 + q * 8);
    }
  float c0r[4][4], zacc[4][4];
#pragma unroll
  for (int c = 0; c < 4; ++c)
#pragma unroll
    for (int r = 0; r < 4; ++r) {
      c0r[c][r] = c0s[rowbase + c * 16 + q * 4 + r];
      zacc[c][r] = 0.0f;
    }
  if (tid < 64) Zl[tid] = 0.0f;
  const unsigned short* BfL = Bf + BF_SPLIT;
  for (int lt = w; lt < 128; lt += 4) {
    size_t b0 = ((size_t)(lt * 2 + 0) * 64 + lane) * 8;
    size_t b1 = ((size_t)(lt * 2 + 1) * 64 + lane) * 8;
    short8 Bh0 = *(const short8*)(Bf + b0);
    short8 Bh1 = *(const short8*)(Bf + b1);
    short8 Bl0 = *(const short8*)(BfL + b0);
    short8 Bl1 = *(const short8*)(BfL + b1);
#pragma unroll
    for (int c = 0; c < 4; ++c) {
      floatx4 y = {0.f, 0.f, 0.f, 0.f};
      y = __builtin_amdgcn_mfma_f32_16x16x32_bf16(Ah[c][0], Bh0, y, 0, 0, 0);
      y = __builtin_amdgcn_mfma_f32_16x16x32_bf16(Ah[c][1], Bh1, y, 0, 0, 0);
      y = __builtin_amdgcn_mfma_f32_16x16x32_bf16(Ah[c][0], Bl0, y, 0, 0, 0);
      y = __builtin_amdgcn_mfma_f32_16x16x32_bf16(Ah[c][1], Bl1, y, 0, 0, 0);
      y = __builtin_amdgcn_mfma_f32_16x16x32_bf16(Al[c][0], Bh0, y, 0, 0, 0);
      y = __builtin_amdgcn_mfma_f32_16x16x32_bf16(Al[c][1], Bh1, y, 0, 0, 0);
#pragma unroll
      for (int r = 0; r < 4; ++r) zacc[c][r] += __expf(y[r] + c0r[c][r]);
    }
  }
  __syncthreads();
#pragma unroll
  for (int c = 0; c < 4; ++c)
#pragma unroll
    for (int r = 0; r < 4; ++r) {
#pragma unroll
      for (int m = 1; m < 16; m <<= 1) zacc[c][r] += __shfl_xor(zacc[c][r], m, 16);
      if (n == 0) atomicAdd(&Zl[c * 16 + q * 4 + r], zacc[c][r]);
    }
  __syncthreads();
  if (tid < 64) c0z[rowbase + tid] = c0s[rowbase + tid] - __logf(Zl[tid]);
}

// ---------------------------------------------------------------- k4: output
// R7 pipeline skeleton, widened to 64 l per block (512 blocks): halves the
// cross-block L2 re-read of A-coefs and V-frags (1.1 GB -> 0.55 GB).
// Wave w: E for s-slice w*16..+16 x 64 l (4 lt x 6 MFMA) -> Es; PV consumes
// LAST period's Es (cross-barrier pipeline); one barrier per tile.
#define K4_LOADA(st_, sl_)                                                           \
  do {                                                                               \
    int rz_ = bh * 2048 + (st_) * 64;                                                \
    size_t srow_ = (size_t)(rz_ + w * 16 + n);                                       \
    Ahs[sl_][0] = *(const short8*)(Ch + srow_ * 64 + qd * 8);                        \
    Ahs[sl_][1] = *(const short8*)(Ch + srow_ * 64 + 32 + qd * 8);                   \
    Als[sl_][0] = *(const short8*)(Cl + srow_ * 64 + qd * 8);                        \
    Als[sl_][1] = *(const short8*)(Cl + srow_ * 64 + 32 + qd * 8);                   \
    c0rs[sl_] = *(const float4*)(c0z + rz_ + w * 16 + qd * 4);                       \
  } while (0)

#define K4_LOADV(st_, sl_)                                                           \
  do {                                                                               \
    size_t vo_ = (((size_t)(bh * 32 + (st_))) * 8 + w * 2) * 512 + lane * 8;         \
    Vhs[sl_][0] = *(const short8*)(Vf + vo_);                                        \
    Vhs[sl_][1] = *(const short8*)(Vf + vo_ + 512);                                  \
    Vls[sl_][0] = *(const short8*)(VfL + vo_);                                       \
    Vls[sl_][1] = *(const short8*)(VfL + vo_ + 512);                                 \
  } while (0)

#define K4_PV(sl_)                                                                   \
  do {                                                                               \
    _Pragma("unroll")                                                                \
    for (int ksp_ = 0; ksp_ < 2; ++ksp_) {                                           \
      short8 Vh_ = Vhs[sl_][ksp_], Vl_ = Vls[sl_][ksp_];                             \
      _Pragma("unroll")                                                              \
      for (int lt_ = 0; lt_ < 4; ++lt_) {                                            \
        short8 E_ = *(const short8*)(&Es[sl_][sw(lt_ * 16 + n, ksp_ * 32 + qd * 8)]);\
        accv[lt_] = __builtin_amdgcn_mfma_f32_16x16x32_bf16(E_, Vh_, accv[lt_],0,0,0);\
        accv[lt_] = __builtin_amdgcn_mfma_f32_16x16x32_bf16(E_, Vl_, accv[lt_],0,0,0);\
      }                                                                              \
    }                                                                                \
  } while (0)

#define K4_ITER(st_, sl_, first_, last_)                                             \
  do {                                                                               \
    float4 cc_ = c0rs[sl_];                                                          \
    _Pragma("unroll")                                                                \
    for (int lt_ = 0; lt_ < 4; ++lt_) {                                              \
      floatx4 y = {0, 0, 0, 0};                                                      \
      y = __builtin_amdgcn_mfma_f32_16x16x32_bf16(Ahs[sl_][0], Bbh[lt_][0], y,0,0,0);\
      y = __builtin_amdgcn_mfma_f32_16x16x32_bf16(Ahs[sl_][1], Bbh[lt_][1], y,0,0,0);\
      y = __builtin_amdgcn_mfma_f32_16x16x32_bf16(Ahs[sl_][0], Bbl[lt_][0], y,0,0,0);\
      y = __builtin_amdgcn_mfma_f32_16x16x32_bf16(Ahs[sl_][1], Bbl[lt_][1], y,0,0,0);\
      y = __builtin_amdgcn_mfma_f32_16x16x32_bf16(Als[sl_][0], Bbh[lt_][0], y,0,0,0);\
      y = __builtin_amdgcn_mfma_f32_16x16x32_bf16(Als[sl_][1], Bbh[lt_][1], y,0,0,0);\
      unsigned short e0_ = f2bf(__expf(y[0] + cc_.x));                               \
      unsigned short e1_ = f2bf(__expf(y[1] + cc_.y));                               \
      unsigned short e2_ = f2bf(__expf(y[2] + cc_.z));                               \
      unsigned short e3_ = f2bf(__expf(y[3] + cc_.w));                               \
      uint2 p_;                                                                      \
      p_.x = (unsigned)e0_ | ((unsigned)e1_ << 16);                                  \
      p_.y = (unsigned)e2_ | ((unsigned)e3_ << 16);                                  \
      *(uint2*)(&Es[sl_][sw(lt_ * 16 + n, w * 16 + qd * 4)]) = p_;                   \
    }                                                                                \
    if (!(last_)) { K4_LOADA((st_) + 1, 1 - (sl_)); }                                \
    if (!(first_)) { K4_PV(1 - (sl_)); }                                             \
    if (!(last_)) { K4_LOADV((st_) + 1, 1 - (sl_)); }                                \
    __syncthreads();                                                                 \
  } while (0)

__launch_bounds__(256, 2)
__global__ void k4_out(const unsigned short* __restrict__ Ch, const unsigned short* __restrict__ Cl,
                       const float* __restrict__ c0z, const unsigned short* __restrict__ Bf,
                       const unsigned short* __restrict__ Vf, float* __restrict__ out) {
  __shared__ unsigned short Es[2][64 * 64];
  int tid = threadIdx.x;
  int w = tid >> 6, lane = tid & 63, qd = lane >> 4, n = lane & 15;
  int bh = blockIdx.x, b = bh >> 3, h = bh & 7;
  int l0 = blockIdx.y * 64, lt0 = blockIdx.y * 4;
  const unsigned short* BfL = Bf + BF_SPLIT;
  const unsigned short* VfL = Vf + VF_PLANE;
  short8 Bbh[4][2], Bbl[4][2];
#pragma unroll
  for (int lt = 0; lt < 4; ++lt)
#pragma unroll
    for (int ksp = 0; ksp < 2; ++ksp) {
      size_t bo = ((size_t)((lt0 + lt) * 2 + ksp) * 64 + lane) * 8;
      Bbh[lt][ksp] = *(const short8*)(Bf + bo);
      Bbl[lt][ksp] = *(const short8*)(BfL + bo);
    }
  floatx4 accv[4];
#pragma unroll
  for (int lt = 0; lt < 4; ++lt) accv[lt] = (floatx4){0.f, 0.f, 0.f, 0.f};
  short8 Ahs[2][2], Als[2][2], Vhs[2][2], Vls[2][2];
  float4 c0rs[2];
  K4_LOADA(0, 0);
  K4_LOADV(0, 0);
  K4_ITER(0, 0, true, false);
  for (int st2 = 0; st2 < 15; ++st2) {
    K4_ITER(2 * st2 + 1, 1, false, false);
    K4_ITER(2 * st2 + 2, 0, false, false);
  }
  K4_ITER(31, 1, false, true);
  K4_PV(1);   // drain: PV of tile 31 (Es[1], V slot 1)
  // Store: accv[lt]: d = w*16 + n ; l = l0 + lt*16 + qd*4 + r ; out [b][d][h][l]
#pragma unroll
  for (int lt = 0; lt < 4; ++lt) {
    size_t base = ((size_t)((b * 64 + w * 16 + n) * 8 + h)) * 2048 + l0 + lt * 16 + qd * 4;
    float4 o4;
    o4.x = accv[lt][0]; o4.y = accv[lt][1]; o4.z = accv[lt][2]; o4.w = accv[lt][3];
    *(float4*)(out + base) = o4;
  }
}

extern "C" void kernel_launch(void* const* d_in, const int* in_sizes, int n_in,
                              void* d_out, int out_size, void* d_ws, size_t ws_size,
                              hipStream_t stream) {
  const float* q = (const float*)d_in[0];
  const float* k = (const float*)d_in[1];
  const float* v = (const float*)d_in[2];
  float* out = (float*)d_out;
  float* ws = (float*)d_ws;
  float* c0s = ws + F_C0S;
  float* c0z = ws + F_C0Z;
  unsigned short* ubase = (unsigned short*)(ws + F_END);
  unsigned short* Ch = ubase + U_CH;
  unsigned short* Cl = ubase + U_CL;
  unsigned short* Bf = ubase + U_BF;
  unsigned short* Vf = ubase + U_VF;

  mega1<<<dim3(1088), dim3(256), 0, stream>>>(q, k, v, Bf, Vf, Ch, Cl, c0s);
  k3_z<<<dim3(512), dim3(256), 0, stream>>>(Ch, Cl, c0s, Bf, c0z);
  k4_out<<<dim3(16, 32), dim3(256), 0, stream>>>(Ch, Cl, c0z, Bf, Vf, out);
}

// Round 11
// 141.122 us; speedup vs baseline: 1.8555x; 1.1097x over previous
//
#include <hip/hip_runtime.h>
#include <math.h>

// B=2, H=8, L=2048, E=512, d=64
constexpr int CL = 2048;
constexpr int NROW = 32768;
constexpr float SCALE = 1.0f / 2048.0f;
constexpr float TWO_PI = 6.283185307179586f;

typedef short short8 __attribute__((ext_vector_type(8)));
typedef float floatx4 __attribute__((ext_vector_type(4)));
typedef _Float16 half8 __attribute__((ext_vector_type(8)));
typedef __fp16 fp16x2 __attribute__((ext_vector_type(2)));   // cvt_pkrtz return type

__device__ inline unsigned short f2bf(float f) {
  union { float f; unsigned u; } c; c.f = f;
  unsigned u = c.u + 0x7FFF + ((c.u >> 16) & 1);
  return (unsigned short)(u >> 16);
}
__device__ inline float bf2f(unsigned short h) {
  union { unsigned u; float f; } c; c.u = ((unsigned)h) << 16;
  return c.f;
}
__device__ inline unsigned short f2h(float f) {
  union { _Float16 h; unsigned short u; } c; c.h = (_Float16)f; return c.u;
}
__device__ inline float h2f(unsigned short u) {
  union { unsigned short u; _Float16 h; } c; c.u = u; return (float)c.h;
}
// XOR swizzle for [rows][64 ushort] LDS tiles: 16B-group g at row r -> g^(r&7).
__device__ inline int sw(int r, int o) {
  return r * 64 + ((((o >> 3) ^ r) & 7) << 3) + (o & 7);
}

// ---------------- workspace ----------------
constexpr size_t F_C0S = 0;
constexpr size_t F_C0Z = F_C0S + NROW;
constexpr size_t F_END = F_C0Z + NROW;
constexpr size_t U_CH  = 0;
constexpr size_t U_CL  = U_CH + (size_t)NROW * 64;
constexpr size_t U_BF  = U_CL + (size_t)NROW * 64;
constexpr size_t U_VF  = U_BF + (size_t)2 * 131072;
constexpr size_t VF_PLANE = 2097152;   // only hi plane used now

// ================================================================ mega launch 1
// blocks [0,64):   Bf basis-fragment table (fp16, single plane)
// blocks [64,576): kv V-fragment build (fp16, single plane)
// blocks [576,1088): fused DFT+coef (DFT in bf16-split, coefs emitted fp16 hi/lo)
__launch_bounds__(256)
__global__ void mega1(const float* __restrict__ q, const float* __restrict__ kin,
                      const float* __restrict__ values,
                      unsigned short* __restrict__ Bf, unsigned short* __restrict__ Vf,
                      unsigned short* __restrict__ Ch, unsigned short* __restrict__ Cl,
                      float* __restrict__ c0s) {
  __shared__ char smem[16640];
  int tid = threadIdx.x;
  int blk = blockIdx.x;
  if (blk < 64) {
    int gid = blk * 256 + tid;
    int lt = gid >> 7, rem = gid & 127, ks = rem >> 6, lane = rem & 63;
    int qd = lane >> 4, n = lane & 15;
    int t = lt * 16 + n;
    size_t base = ((size_t)((lt * 2 + ks) * 64 + lane)) * 8;
    for (int j = 0; j < 8; ++j) {
      int kr = ks * 32 + qd * 8 + j;
      int freq = (kr < 32) ? (kr + 1) : (kr - 31);
      int ph = (freq * t) & (CL - 1);
      float ang = (float)ph * (TWO_PI / (float)CL);
      float val = (kr < 32) ? cosf(ang) : sinf(ang);
      Bf[base + j] = f2h(val);
    }
    return;
  }
  if (blk < 576) {
    // V tile [64 s][64 d] -> B-operand frags (fp16): frag = dt*2+ksp;
    // elem[lane*8+j] = V[s = ksp*32 + qd*8 + j][d = dt*16 + n]
    float* Vt = (float*)smem;                    // [64][65]
    int idx = blk - 64;
    int bh = idx >> 5, st = idx & 31;
    int b = bh >> 3, h = bh & 7;
    {
      int sl = tid >> 2, dq = (tid & 3) * 16;
      const float4* src = (const float4*)(values + ((size_t)(b * 2048 + st * 64 + sl)) * 512 + h * 64 + dq);
#pragma unroll
      for (int m = 0; m < 4; ++m) {
        float4 t4 = src[m];
        int base = sl * 65 + dq + m * 4;
        Vt[base] = t4.x; Vt[base + 1] = t4.y; Vt[base + 2] = t4.z; Vt[base + 3] = t4.w;
      }
    }
    __syncthreads();
#pragma unroll
    for (int iter = 0; iter < 2; ++iter) {
      int it = iter * 256 + tid;
      int lane = it & 63, ksp = (it >> 6) & 1, dt = it >> 7;
      int qd = lane >> 4, n = lane & 15;
      int d = dt * 16 + n;
      short8 hi;
#pragma unroll
      for (int j = 0; j < 8; ++j)
        hi[j] = (short)f2h(Vt[(ksp * 32 + qd * 8 + j) * 65 + d]);
      size_t off = (((size_t)(bh * 32 + st)) * 8 + dt * 2 + ksp) * 512 + lane * 8;
      *(short8*)(Vf + off) = hi;
    }
    return;
  }
  // ---- fused DFT + coef. Block = 8 s x 8 h of one b (64 rows).
  unsigned short* Tws = (unsigned short*)smem;   // 4 planes x 2048 (bf16 split)
  {
    int g0 = tid * 8;
    int lane_g = (g0 >> 3) & 63, ksp_g = (g0 >> 9) & 1, ct_g = g0 >> 10;
    int f = ct_g * 16 + (lane_g & 15);
    int cb = ksp_g * 32 + ((lane_g >> 4) & 3) * 8;
#pragma unroll
    for (int j = 0; j < 8; ++j) {
      float ang = (float)((f * (cb + j)) & 63) * (TWO_PI / 64.0f);
      float s1, c1;
      sincosf(ang, &s1, &c1);
      float re = c1, im = -s1;
      unsigned short rh = f2bf(re), ih = f2bf(im);
      Tws[g0 + j] = rh;        Tws[2048 + g0 + j] = f2bf(re - bf2f(rh));
      Tws[4096 + g0 + j] = ih; Tws[6144 + g0 + j] = f2bf(im - bf2f(ih));
    }
  }
  __syncthreads();
  int w = tid >> 6, lane = tid & 63, qd = lane >> 4, n = lane & 15;
  int blk1 = blk - 576;
  int b = blk1 >> 8, s0 = (blk1 & 255) * 8;
  int sA = s0 + w * 2 + (n >> 3), hA = n & 7;
  const float* qp = q + ((size_t)(b * 2048 + sA)) * 512 + hA * 64 + qd * 8;
  const float* kp = kin + ((size_t)(b * 2048 + sA)) * 512 + hA * 64 + qd * 8;
  float qv[16], kv[16];
#pragma unroll
  for (int ksp = 0; ksp < 2; ++ksp) {
    float4 a0 = *(const float4*)(qp + ksp * 32);
    float4 a1 = *(const float4*)(qp + ksp * 32 + 4);
    float4 b0 = *(const float4*)(kp + ksp * 32);
    float4 b1 = *(const float4*)(kp + ksp * 32 + 4);
    qv[ksp*8+0]=a0.x; qv[ksp*8+1]=a0.y; qv[ksp*8+2]=a0.z; qv[ksp*8+3]=a0.w;
    qv[ksp*8+4]=a1.x; qv[ksp*8+5]=a1.y; qv[ksp*8+6]=a1.z; qv[ksp*8+7]=a1.w;
    kv[ksp*8+0]=b0.x; kv[ksp*8+1]=b0.y; kv[ksp*8+2]=b0.z; kv[ksp*8+3]=b0.w;
    kv[ksp*8+4]=b1.x; kv[ksp*8+5]=b1.y; kv[ksp*8+6]=b1.z; kv[ksp*8+7]=b1.w;
  }
  float aq = 0.0f, ak = 0.0f;
#pragma unroll
  for (int i = 0; i < 16; ++i) {
    float sg = (i & 1) ? -1.0f : 1.0f;
    aq += sg * qv[i]; ak += sg * kv[i];
  }
  aq += __shfl_xor(aq, 16); aq += __shfl_xor(aq, 32);
  ak += __shfl_xor(ak, 16); ak += __shfl_xor(ak, 32);
  short8 Aqh[2], Aql[2], Akh[2], Akl[2];
#pragma unroll
  for (int ksp = 0; ksp < 2; ++ksp) {
#pragma unroll
    for (int j = 0; j < 8; ++j) {
      unsigned short hq = f2bf(qv[ksp*8+j]);
      Aqh[ksp][j] = (short)hq; Aql[ksp][j] = (short)f2bf(qv[ksp*8+j] - bf2f(hq));
      unsigned short hk = f2bf(kv[ksp*8+j]);
      Akh[ksp][j] = (short)hk; Akl[ksp][j] = (short)f2bf(kv[ksp*8+j] - bf2f(hk));
    }
  }
  float lmr[4] = {0,0,0,0};
  float c0v[4] = {0,0,0,0};
  int hC = (qd * 4) & 7;
  int sC = s0 + w * 2 + (qd >> 1);
#pragma unroll
  for (int ct = 0; ct < 2; ++ct) {
    short8 Brh[2], Brl[2], Bih[2], Bil[2];
#pragma unroll
    for (int ksp = 0; ksp < 2; ++ksp) {
      size_t off = (size_t)ct * 1024 + ksp * 512 + lane * 8;
      Brh[ksp] = *(const short8*)(Tws + off);
      Brl[ksp] = *(const short8*)(Tws + 2048 + off);
      Bih[ksp] = *(const short8*)(Tws + 4096 + off);
      Bil[ksp] = *(const short8*)(Tws + 6144 + off);
    }
    floatx4 qre = {0,0,0,0}, qim = {0,0,0,0}, kre = {0,0,0,0}, kim = {0,0,0,0};
#pragma unroll
    for (int ksp = 0; ksp < 2; ++ksp) {
      qre = __builtin_amdgcn_mfma_f32_16x16x32_bf16(Aqh[ksp], Brh[ksp], qre, 0,0,0);
      qre = __builtin_amdgcn_mfma_f32_16x16x32_bf16(Aqh[ksp], Brl[ksp], qre, 0,0,0);
      qre = __builtin_amdgcn_mfma_f32_16x16x32_bf16(Aql[ksp], Brh[ksp], qre, 0,0,0);
      qim = __builtin_amdgcn_mfma_f32_16x16x32_bf16(Aqh[ksp], Bih[ksp], qim, 0,0,0);
      qim = __builtin_amdgcn_mfma_f32_16x16x32_bf16(Aqh[ksp], Bil[ksp], qim, 0,0,0);
      qim = __builtin_amdgcn_mfma_f32_16x16x32_bf16(Aql[ksp], Bih[ksp], qim, 0,0,0);
      kre = __builtin_amdgcn_mfma_f32_16x16x32_bf16(Akh[ksp], Brh[ksp], kre, 0,0,0);
      kre = __builtin_amdgcn_mfma_f32_16x16x32_bf16(Akh[ksp], Brl[ksp], kre, 0,0,0);
      kre = __builtin_amdgcn_mfma_f32_16x16x32_bf16(Akl[ksp], Brh[ksp], kre, 0,0,0);
      kim = __builtin_amdgcn_mfma_f32_16x16x32_bf16(Akh[ksp], Bih[ksp], kim, 0,0,0);
      kim = __builtin_amdgcn_mfma_f32_16x16x32_bf16(Akh[ksp], Bil[ksp], kim, 0,0,0);
      kim = __builtin_amdgcn_mfma_f32_16x16x32_bf16(Akl[ksp], Bih[ksp], kim, 0,0,0);
    }
    float xre[4], xim[4], tre = 0, tim = 0;
#pragma unroll
    for (int r = 0; r < 4; ++r) {
      xre[r] = qre[r] * kre[r] + qim[r] * kim[r];
      xim[r] = qim[r] * kre[r] - qre[r] * kim[r];
      tre += xre[r]; tim += xim[r];
    }
    tre += __shfl_xor(tre, 16);
    tim += __shfl_xor(tim, 16);
    float mre = tre * 0.125f, mim = tim * 0.125f;
#pragma unroll
    for (int r = 0; r < 4; ++r) {
      float yre = xre[r] - mre, yim = xim[r] - mim;
      if (ct == 0 && n == 0) {
        c0v[r] = yre * SCALE;
      } else {
        int f = ct * 16 + n;
        float a = 2.0f * yre * SCALE, bb = -2.0f * yim * SCALE;
        size_t rowid = (size_t)((b * 8 + hC + r) * 2048 + sC);
        unsigned short ah = f2h(a);
        Ch[rowid * 64 + f - 1] = ah;
        Cl[rowid * 64 + f - 1] = f2h(a - h2f(ah));
        unsigned short bh2 = f2h(bb);
        Ch[rowid * 64 + 32 + f - 1] = bh2;
        Cl[rowid * 64 + 32 + f - 1] = f2h(bb - h2f(bh2));
        lmr[r] += fabsf(a) + fabsf(bb);
      }
    }
  }
  float X32 = aq * ak;
  float m32 = X32;
  m32 += __shfl_xor(m32, 1); m32 += __shfl_xor(m32, 2); m32 += __shfl_xor(m32, 4);
  float A32 = 2.0f * (X32 - m32 * 0.125f) * SCALE;
  if (qd == 0) {
    size_t rowid = (size_t)((b * 8 + (n & 7)) * 2048 + s0 + w * 2 + (n >> 3));
    unsigned short ah = f2h(A32);
    Ch[rowid * 64 + 31] = ah;
    Cl[rowid * 64 + 31] = f2h(A32 - h2f(ah));
    Ch[rowid * 64 + 63] = 0;
    Cl[rowid * 64 + 63] = 0;
  }
  float absA32 = fabsf(A32);
#pragma unroll
  for (int r = 0; r < 4; ++r) {
    lmr[r] += __shfl_xor(lmr[r], 1);
    lmr[r] += __shfl_xor(lmr[r], 2);
    lmr[r] += __shfl_xor(lmr[r], 4);
    lmr[r] += __shfl_xor(lmr[r], 8);
  }
  int qb = lane & 48;
#pragma unroll
  for (int r = 0; r < 4; ++r) {
    float a32r = __shfl(absA32, qb + (qb >> 2) + r);
    if (n == 0) {
      float M = fabsf(c0v[r]) + lmr[r] + a32r;
      size_t rowid = (size_t)((b * 8 + hC + r) * 2048 + sC);
      c0s[rowid] = c0v[r] - M;
    }
  }
}

// ---------------------------------------------------------------- k3: c0z = c0 - log(Z)
// fp16 logit GEMM: 4 MFMA per (c, lt) instead of 6.
__launch_bounds__(256)
__global__ void k3_z(const unsigned short* __restrict__ Ch, const unsigned short* __restrict__ Cl,
                     const float* __restrict__ c0s, const unsigned short* __restrict__ Bf,
                     float* __restrict__ c0z) {
  __shared__ float Zl[64];
  int tid = threadIdx.x;
  int w = tid >> 6, lane = tid & 63, q = lane >> 4, n = lane & 15;
  int rowbase = blockIdx.x * 64;
  half8 Ah[4][2], Al[4][2];
#pragma unroll
  for (int c = 0; c < 4; ++c)
#pragma unroll
    for (int ksp = 0; ksp < 2; ++ksp) {
      size_t srow = (size_t)(rowbase + c * 16 + n);
      Ah[c][ksp] = *(const half8*)(Ch + srow * 64 + ksp * 32 + q * 8);
      Al[c][ksp] = *(const half8*)(Cl + srow * 64 + ksp * 32 + q * 8);
    }
  float c0r[4][4], zacc[4][4];
#pragma unroll
  for (int c = 0; c < 4; ++c)
#pragma unroll
    for (int r = 0; r < 4; ++r) {
      c0r[c][r] = c0s[rowbase + c * 16 + q * 4 + r];
      zacc[c][r] = 0.0f;
    }
  if (tid < 64) Zl[tid] = 0.0f;
  for (int lt = w; lt < 128; lt += 4) {
    size_t b0 = ((size_t)(lt * 2 + 0) * 64 + lane) * 8;
    size_t b1 = ((size_t)(lt * 2 + 1) * 64 + lane) * 8;
    half8 Bh0 = *(const half8*)(Bf + b0);
    half8 Bh1 = *(const half8*)(Bf + b1);
#pragma unroll
    for (int c = 0; c < 4; ++c) {
      floatx4 y = {0.f, 0.f, 0.f, 0.f};
      y = __builtin_amdgcn_mfma_f32_16x16x32_f16(Ah[c][0], Bh0, y, 0, 0, 0);
      y = __builtin_amdgcn_mfma_f32_16x16x32_f16(Ah[c][1], Bh1, y, 0, 0, 0);
      y = __builtin_amdgcn_mfma_f32_16x16x32_f16(Al[c][0], Bh0, y, 0, 0, 0);
      y = __builtin_amdgcn_mfma_f32_16x16x32_f16(Al[c][1], Bh1, y, 0, 0, 0);
#pragma unroll
      for (int r = 0; r < 4; ++r) zacc[c][r] += __expf(y[r] + c0r[c][r]);
    }
  }
  __syncthreads();
#pragma unroll
  for (int c = 0; c < 4; ++c)
#pragma unroll
    for (int r = 0; r < 4; ++r) {
#pragma unroll
      for (int m = 1; m < 16; m <<= 1) zacc[c][r] += __shfl_xor(zacc[c][r], m, 16);
      if (n == 0) atomicAdd(&Zl[c * 16 + q * 4 + r], zacc[c][r]);
    }
  __syncthreads();
  if (tid < 64) c0z[rowbase + tid] = c0s[rowbase + tid] - __logf(Zl[tid]);
}

// ---------------------------------------------------------------- k4: output
// R9 skeleton (64-l blocks, cross-barrier PV pipeline), fp16 everywhere:
// E-phase 16 MFMA/tile/wave (fp16 hi/lo coef x fp16 basis), Es fp16 via
// cvt_pkrtz, PV 8 MFMA/tile/wave (fp16 V single plane).
#define K4_LOADA(st_, sl_)                                                           \
  do {                                                                               \
    int rz_ = bh * 2048 + (st_) * 64;                                                \
    size_t srow_ = (size_t)(rz_ + w * 16 + n);                                       \
    Ahs[sl_][0] = *(const half8*)(Ch + srow_ * 64 + qd * 8);                         \
    Ahs[sl_][1] = *(const half8*)(Ch + srow_ * 64 + 32 + qd * 8);                    \
    Als[sl_][0] = *(const half8*)(Cl + srow_ * 64 + qd * 8);                         \
    Als[sl_][1] = *(const half8*)(Cl + srow_ * 64 + 32 + qd * 8);                    \
    c0rs[sl_] = *(const float4*)(c0z + rz_ + w * 16 + qd * 4);                       \
  } while (0)

#define K4_LOADV(st_, sl_)                                                           \
  do {                                                                               \
    size_t vo_ = (((size_t)(bh * 32 + (st_))) * 8 + w * 2) * 512 + lane * 8;         \
    Vhs[sl_][0] = *(const half8*)(Vf + vo_);                                         \
    Vhs[sl_][1] = *(const half8*)(Vf + vo_ + 512);                                   \
  } while (0)

#define K4_PV(sl_)                                                                   \
  do {                                                                               \
    _Pragma("unroll")                                                                \
    for (int ksp_ = 0; ksp_ < 2; ++ksp_) {                                           \
      half8 Vh_ = Vhs[sl_][ksp_];                                                    \
      _Pragma("unroll")                                                              \
      for (int lt_ = 0; lt_ < 4; ++lt_) {                                            \
        half8 E_ = *(const half8*)(&Es[sl_][sw(lt_ * 16 + n, ksp_ * 32 + qd * 8)]);  \
        accv[lt_] = __builtin_amdgcn_mfma_f32_16x16x32_f16(E_, Vh_, accv[lt_],0,0,0);\
      }                                                                              \
    }                                                                                \
  } while (0)

#define K4_ITER(st_, sl_, first_, last_)                                             \
  do {                                                                               \
    float4 cc_ = c0rs[sl_];                                                          \
    _Pragma("unroll")                                                                \
    for (int lt_ = 0; lt_ < 4; ++lt_) {                                              \
      floatx4 y = {0, 0, 0, 0};                                                      \
      y = __builtin_amdgcn_mfma_f32_16x16x32_f16(Ahs[sl_][0], Bbh[lt_][0], y,0,0,0); \
      y = __builtin_amdgcn_mfma_f32_16x16x32_f16(Ahs[sl_][1], Bbh[lt_][1], y,0,0,0); \
      y = __builtin_amdgcn_mfma_f32_16x16x32_f16(Als[sl_][0], Bbh[lt_][0], y,0,0,0); \
      y = __builtin_amdgcn_mfma_f32_16x16x32_f16(Als[sl_][1], Bbh[lt_][1], y,0,0,0); \
      union { fp16x2 h; unsigned u; } pk0_, pk1_;                                    \
      pk0_.h = __builtin_amdgcn_cvt_pkrtz(__expf(y[0] + cc_.x), __expf(y[1] + cc_.y));\
      pk1_.h = __builtin_amdgcn_cvt_pkrtz(__expf(y[2] + cc_.z), __expf(y[3] + cc_.w));\
      uint2 p_;                                                                      \
      p_.x = pk0_.u; p_.y = pk1_.u;                                                  \
      *(uint2*)(&Es[sl_][sw(lt_ * 16 + n, w * 16 + qd * 4)]) = p_;                   \
    }                                                                                \
    if (!(last_)) { K4_LOADA((st_) + 1, 1 - (sl_)); }                                \
    if (!(first_)) { K4_PV(1 - (sl_)); }                                             \
    if (!(last_)) { K4_LOADV((st_) + 1, 1 - (sl_)); }                                \
    __syncthreads();                                                                 \
  } while (0)

__launch_bounds__(256, 2)
__global__ void k4_out(const unsigned short* __restrict__ Ch, const unsigned short* __restrict__ Cl,
                       const float* __restrict__ c0z, const unsigned short* __restrict__ Bf,
                       const unsigned short* __restrict__ Vf, float* __restrict__ out) {
  __shared__ unsigned short Es[2][64 * 64];
  int tid = threadIdx.x;
  int w = tid >> 6, lane = tid & 63, qd = lane >> 4, n = lane & 15;
  int bh = blockIdx.x, b = bh >> 3, h = bh & 7;
  int l0 = blockIdx.y * 64, lt0 = blockIdx.y * 4;
  half8 Bbh[4][2];
#pragma unroll
  for (int lt = 0; lt < 4; ++lt)
#pragma unroll
    for (int ksp = 0; ksp < 2; ++ksp) {
      size_t bo = ((size_t)((lt0 + lt) * 2 + ksp) * 64 + lane) * 8;
      Bbh[lt][ksp] = *(const half8*)(Bf + bo);
    }
  floatx4 accv[4];
#pragma unroll
  for (int lt = 0; lt < 4; ++lt) accv[lt] = (floatx4){0.f, 0.f, 0.f, 0.f};
  half8 Ahs[2][2], Als[2][2], Vhs[2][2];
  float4 c0rs[2];
  K4_LOADA(0, 0);
  K4_LOADV(0, 0);
  K4_ITER(0, 0, true, false);
  for (int st2 = 0; st2 < 15; ++st2) {
    K4_ITER(2 * st2 + 1, 1, false, false);
    K4_ITER(2 * st2 + 2, 0, false, false);
  }
  K4_ITER(31, 1, false, true);
  K4_PV(1);   // drain: PV of tile 31 (Es[1], V slot 1)
  // Store: accv[lt]: d = w*16 + n ; l = l0 + lt*16 + qd*4 + r ; out [b][d][h][l]
#pragma unroll
  for (int lt = 0; lt < 4; ++lt) {
    size_t base = ((size_t)((b * 64 + w * 16 + n) * 8 + h)) * 2048 + l0 + lt * 16 + qd * 4;
    float4 o4;
    o4.x = accv[lt][0]; o4.y = accv[lt][1]; o4.z = accv[lt][2]; o4.w = accv[lt][3];
    *(float4*)(out + base) = o4;
  }
}

extern "C" void kernel_launch(void* const* d_in, const int* in_sizes, int n_in,
                              void* d_out, int out_size, void* d_ws, size_t ws_size,
                              hipStream_t stream) {
  const float* q = (const float*)d_in[0];
  const float* k = (const float*)d_in[1];
  const float* v = (const float*)d_in[2];
  float* out = (float*)d_out;
  float* ws = (float*)d_ws;
  float* c0s = ws + F_C0S;
  float* c0z = ws + F_C0Z;
  unsigned short* ubase = (unsigned short*)(ws + F_END);
  unsigned short* Ch = ubase + U_CH;
  unsigned short* Cl = ubase + U_CL;
  unsigned short* Bf = ubase + U_BF;
  unsigned short* Vf = ubase + U_VF;

  mega1<<<dim3(1088), dim3(256), 0, stream>>>(q, k, v, Bf, Vf, Ch, Cl, c0s);
  k3_z<<<dim3(512), dim3(256), 0, stream>>>(Ch, Cl, c0s, Bf, c0z);
  k4_out<<<dim3(16, 32), dim3(256), 0, stream>>>(Ch, Cl, c0z, Bf, Vf, out);
}